// Round 14
// baseline (281.748 us; speedup 1.0000x reference)
//
#include <hip/hip_runtime.h>

#define HID 128
#define NNODE 10000
#define KN 16
#define ROWS 80000    // BATCH * NNODE
#define NTILES 2500   // ROWS / 32
#define ANCH 313      // chunks per (b, col-half)
#define AGRID 5008    // 8 * 2 * ANCH aggr blocks
#define COGRID 6260   // AGRID + 1252 embed blocks interleaved (bid%5==4)

typedef __attribute__((ext_vector_type(8))) short short8;   // 8 bf16 (4 VGPRs)
typedef __attribute__((ext_vector_type(4))) float f32x4;
typedef __attribute__((ext_vector_type(2))) float f32x2;
typedef __attribute__((ext_vector_type(2))) unsigned int u32x2;

__device__ __forceinline__ unsigned short f2b(float f) {
    unsigned u = __float_as_uint(f);
    u += 0x7FFFu + ((u >> 16) & 1u);       // round-to-nearest-even
    return (unsigned short)(u >> 16);
}

// Weight transpose+convert: W1t[128][64], W2t[128][128], Wu1t[128][256],
// Wu2t384[128][384] (k<128->Wu2[k]; 128..383->Wu2[k-128]), Wu2t256 (fallback).
__global__ __launch_bounds__(256) void wconv_all(
    const float* __restrict__ W1, const float* __restrict__ W2,
    const float* __restrict__ Wu1, const float* __restrict__ Wu2,
    unsigned short* __restrict__ W1t, unsigned short* __restrict__ W2t,
    unsigned short* __restrict__ Wu1t, unsigned short* __restrict__ Wu2t384,
    unsigned short* __restrict__ Wu2t256) {
    int idx = blockIdx.x * 256 + threadIdx.x;   // < 139264
    if (idx < 8192) {
        int n = idx & 127, k = idx >> 7;
        W1t[n * 64 + k] = f2b(W1[k * 128 + n]);
    } else if (idx < 24576) {
        int off = idx - 8192; int n = off & 127, k = off >> 7;
        W2t[n * 128 + k] = f2b(W2[k * 128 + n]);
    } else if (idx < 57344) {
        int off = idx - 24576; int n = off & 127, k = off >> 7;
        Wu1t[n * 256 + k] = f2b(Wu1[k * 128 + n]);
    } else if (idx < 106496) {
        int off = idx - 57344; int n = off % 128, k = off / 128;   // k<384
        int sr = k < 256 ? (k & 127) : (k - 128);
        Wu2t384[n * 384 + k] = f2b(Wu2[sr * 128 + n]);
    } else {
        int off = idx - 106496; int n = off & 127, k = off >> 7;
        Wu2t256[n * 256 + k] = f2b(Wu2[k * 128 + n]);
    }
}

// ---- embed role: Y[r][:] = relu(X@W + b); transposed-operand MFMA,
// persistent W-frags, stride loop, 2-deep pipeline. T >= NTILES -> (A1,Y1).
template<int K, bool AF32>
__device__ __forceinline__ void embed_role(
    int lb, int stride, int tot,
    const void* __restrict__ A0, const void* __restrict__ A1,
    const unsigned short* __restrict__ Wt, const float* __restrict__ bias,
    unsigned short* __restrict__ Y0, unsigned short* __restrict__ Y1) {
    const int t = threadIdx.x, w = t >> 6, lane = t & 63;
    const int lrow = lane & 15, lk = lane >> 4;
    const int rs = w & 1, ng = w >> 1;
    const int col0 = ng * 32;

    short8 wf[2][K / 32];
    f32x4 bv[2];
#pragma unroll
    for (int p = 0; p < 2; ++p) {
        bv[p] = *(const f32x4*)(bias + col0 + p * 16 + lk * 4);
#pragma unroll
        for (int kt = 0; kt < K / 32; ++kt)
            wf[p][kt] = *(const short8*)(Wt + (col0 + p * 16 + lrow) * K + kt * 32 + lk * 8);
    }

    int T = lb;
    if (T >= tot) return;

    auto loadx = [&](int TT, short8* xf) {
        const int half = TT >= NTILES;
        const void* A = half ? A1 : A0;
        const int row = (TT - half * NTILES) * 32 + rs * 16 + lrow;
        if constexpr (AF32) {
            const float* X = (const float*)A + (size_t)row * K;
#pragma unroll
            for (int kt = 0; kt < K / 32; ++kt) {
                f32x4 f0 = *(const f32x4*)(X + kt * 32 + lk * 8);
                f32x4 f1 = *(const f32x4*)(X + kt * 32 + lk * 8 + 4);
                short8 v;
#pragma unroll
                for (int e = 0; e < 4; ++e) { v[e] = (short)f2b(f0[e]); v[4 + e] = (short)f2b(f1[e]); }
                xf[kt] = v;
            }
        } else {
            const unsigned short* X = (const unsigned short*)A + (size_t)row * K;
#pragma unroll
            for (int kt = 0; kt < K / 32; ++kt)
                xf[kt] = *(const short8*)(X + kt * 32 + lk * 8);
        }
    };

    short8 xf[K / 32], xn[K / 32];
    loadx(T, xf);
    for (;;) {
        const int Tn = T + stride;
        const bool more = Tn < tot;
        if (more) loadx(Tn, xn);

        const int half = T >= NTILES;
        unsigned short* Y = half ? Y1 : Y0;
        const int row = (T - half * NTILES) * 32 + rs * 16 + lrow;
#pragma unroll
        for (int p = 0; p < 2; ++p) {
            f32x4 acc = {0.f, 0.f, 0.f, 0.f};
#pragma unroll
            for (int kt = 0; kt < K / 32; ++kt)
                acc = __builtin_amdgcn_mfma_f32_16x16x32_bf16(wf[p][kt], xf[kt], acc, 0, 0, 0);
            float v0 = acc[0] + bv[p][0]; v0 = v0 > 0.f ? v0 : 0.f;
            float v1 = acc[1] + bv[p][1]; v1 = v1 > 0.f ? v1 : 0.f;
            float v2 = acc[2] + bv[p][2]; v2 = v2 > 0.f ? v2 : 0.f;
            float v3 = acc[3] + bv[p][3]; v3 = v3 > 0.f ? v3 : 0.f;
            u32x2 ov = {(unsigned)f2b(v0) | ((unsigned)f2b(v1) << 16),
                        (unsigned)f2b(v2) | ((unsigned)f2b(v3) << 16)};
            *(u32x2*)(Y + (size_t)row * HID + col0 + p * 16 + lk * 4) = ov;
        }
        if (!more) break;
#pragma unroll
        for (int kt = 0; kt < K / 32; ++kt) xf[kt] = xn[kt];
        T = Tn;
    }
}

// ---- aggr role: 32 rows/block, 16 thr/row x 8B, col-half split.
// B-MAJOR aid mapping: b = aid/626 -> any resident block window touches
// <=2 slices (~2.6MB), L2-fit on every XCD without affinity assumptions.
template<bool DUAL>
__device__ __forceinline__ void aggr_role(
    const unsigned short* __restrict__ SE, const unsigned short* __restrict__ IE,
    const int* __restrict__ sidx, const int* __restrict__ iidx,
    unsigned short* __restrict__ G, int aid) {
    __shared__ int sh[32][33];
    const int t = threadIdx.x;
    const int b = aid / 626;
    const int rem = aid - b * 626;
    const int h = rem / ANCH;
    const int c = rem - h * ANCH;
    const int n0 = c * 32;

    if constexpr (DUAL) {
#pragma unroll
        for (int q = 0; q < 2; ++q) {
            const int e = t + q * 512;
            const int r = e >> 5, k = e & 31;
            int nr = n0 + r; if (nr > NNODE - 1) nr = NNODE - 1;
            sh[r][k] = (k < KN) ? sidx[nr * KN + k] : iidx[nr * KN + (k - KN)];
        }
    } else {
        const int r = t >> 4, k = t & 15;
        int nr = n0 + r; if (nr > NNODE - 1) nr = NNODE - 1;
        sh[r][k] = sidx[nr * KN + k];
    }
    __syncthreads();

    const int r = t >> 4, p = t & 15;
    const int col0 = h * 64 + p * 4;
    const int n = n0 + r;
    const size_t base = (size_t)b * NNODE * HID + col0;

    f32x2 a0 = {0.f, 0.f}, a1 = {0.f, 0.f};
    {
        u32x2 vs[16];
#pragma unroll
        for (int j = 0; j < 16; ++j)
            vs[j] = *(const u32x2*)(SE + base + (size_t)sh[r][j] * HID);
#pragma unroll
        for (int j = 0; j < 16; ++j) {
            unsigned u0 = vs[j][0], u1 = vs[j][1];
            a0 += (f32x2){__uint_as_float(u0 << 16), __uint_as_float(u0 & 0xffff0000u)};
            a1 += (f32x2){__uint_as_float(u1 << 16), __uint_as_float(u1 & 0xffff0000u)};
        }
    }
    if constexpr (DUAL) {
        u32x2 vi[16];
#pragma unroll
        for (int j = 0; j < 16; ++j)
            vi[j] = *(const u32x2*)(IE + base + (size_t)sh[r][16 + j] * HID);
#pragma unroll
        for (int j = 0; j < 16; ++j) {
            unsigned u0 = vi[j][0], u1 = vi[j][1];
            a0 += (f32x2){__uint_as_float(u0 << 16), __uint_as_float(u0 & 0xffff0000u)};
            a1 += (f32x2){__uint_as_float(u1 << 16), __uint_as_float(u1 & 0xffff0000u)};
        }
    }

    if (n < NNODE) {
        u32x2 ov = {(unsigned)f2b(a0.x) | ((unsigned)f2b(a0.y) << 16),
                    (unsigned)f2b(a1.x) | ((unsigned)f2b(a1.y) << 16)};
        *(u32x2*)(G + ((size_t)b * NNODE + n) * HID + col0) = ov;
    }
}

// ---- update role: Y = relu([G0|G1|H] @ Wut^T + bu). KK=256: [G0|H];
// KK=384: [G0|G1|H] with duplicated aggr weight rows (sum via MFMA).
template<int KK>
__device__ __forceinline__ void update_role(
    int lb, int stride,
    const unsigned short* __restrict__ G0, const unsigned short* __restrict__ G1,
    const unsigned short* __restrict__ H,
    const unsigned short* __restrict__ Wut, const float* __restrict__ bu,
    float* __restrict__ Yf, unsigned short* __restrict__ Yb, int writeb) {
    const int t = threadIdx.x, w = t >> 6, lane = t & 63;
    const int lrow = lane & 15, lk = lane >> 4;
    const int rs = w & 1, ng = w >> 1;
    const int col0 = ng * 32;
    constexpr int NF = KK / 32;

    short8 wf[2][NF];
    f32x4 bv[2];
#pragma unroll
    for (int p = 0; p < 2; ++p) {
        bv[p] = *(const f32x4*)(bu + col0 + p * 16 + lk * 4);
#pragma unroll
        for (int kt = 0; kt < NF; ++kt)
            wf[p][kt] = *(const short8*)(Wut + (col0 + p * 16 + lrow) * KK + kt * 32 + lk * 8);
    }

    for (int T = lb; T < NTILES; T += stride) {
        const int row = T * 32 + rs * 16 + lrow;
        short8 xf[NF];
#pragma unroll
        for (int kt = 0; kt < 4; ++kt) {
            xf[kt] = *(const short8*)(G0 + (size_t)row * HID + kt * 32 + lk * 8);
            if constexpr (KK == 384) {
                xf[4 + kt] = *(const short8*)(G1 + (size_t)row * HID + kt * 32 + lk * 8);
                xf[8 + kt] = *(const short8*)(H + (size_t)row * HID + kt * 32 + lk * 8);
            } else {
                xf[4 + kt] = *(const short8*)(H + (size_t)row * HID + kt * 32 + lk * 8);
            }
        }
#pragma unroll
        for (int p = 0; p < 2; ++p) {
            f32x4 acc = {0.f, 0.f, 0.f, 0.f};
#pragma unroll
            for (int kt = 0; kt < NF; ++kt)
                acc = __builtin_amdgcn_mfma_f32_16x16x32_bf16(wf[p][kt], xf[kt], acc, 0, 0, 0);
            f32x4 o;
#pragma unroll
            for (int j = 0; j < 4; ++j) {
                float v = acc[j] + bv[p][j];
                o[j] = v > 0.f ? v : 0.f;
            }
            *(f32x4*)(Yf + (size_t)row * HID + col0 + p * 16 + lk * 4) = o;
            if (writeb) {
                u32x2 ov = {(unsigned)f2b(o[0]) | ((unsigned)f2b(o[1]) << 16),
                            (unsigned)f2b(o[2]) | ((unsigned)f2b(o[3]) << 16)};
                *(u32x2*)(Yb + (size_t)row * HID + col0 + p * 16 + lk * 4) = ov;
            }
        }
    }
}

// ---------------- kernels ----------------
__global__ __launch_bounds__(512) void k_embed1(
    const float* __restrict__ state, const float* __restrict__ internal,
    const unsigned short* __restrict__ W1t, const float* __restrict__ b1,
    unsigned short* __restrict__ Y0, unsigned short* __restrict__ Y1) {
    embed_role<64, true>(blockIdx.x, gridDim.x, 2 * NTILES, state, internal, W1t, b1, Y0, Y1);
}

// co1: interleaved [aggr-dual 4/5] + [se2-embed 1/5]
__global__ __launch_bounds__(512) void k_co1(
    const unsigned short* __restrict__ SE, const unsigned short* __restrict__ IE,
    const int* __restrict__ sidx, const int* __restrict__ iidx,
    unsigned short* __restrict__ G,
    const unsigned short* __restrict__ W2t, const float* __restrict__ b2,
    unsigned short* __restrict__ se2) {
    const int bid = blockIdx.x;
    if (bid % 5 == 4)
        embed_role<128, false>(bid / 5, 1252, NTILES, SE, nullptr, W2t, b2, se2, nullptr);
    else
        aggr_role<true>(SE, IE, sidx, iidx, G, bid - (bid + 1) / 5);
}

// co2: interleaved [aggr2-SE single 4/5] + [ie2-embed 1/5]
__global__ __launch_bounds__(512) void k_co2(
    const unsigned short* __restrict__ se2, const int* __restrict__ sidx,
    unsigned short* __restrict__ Gs,
    const unsigned short* __restrict__ hu1b,
    const unsigned short* __restrict__ W2t, const float* __restrict__ b2,
    unsigned short* __restrict__ ie2) {
    const int bid = blockIdx.x;
    if (bid % 5 == 4)
        embed_role<128, false>(bid / 5, 1252, NTILES, hu1b, nullptr, W2t, b2, ie2, nullptr);
    else
        aggr_role<false>(se2, nullptr, sidx, nullptr, Gs, bid - (bid + 1) / 5);
}

__global__ __launch_bounds__(512) void k_aggrS(
    const unsigned short* __restrict__ SRC, const int* __restrict__ idx,
    unsigned short* __restrict__ G) {
    aggr_role<false>(SRC, nullptr, idx, nullptr, G, blockIdx.x);
}

__global__ __launch_bounds__(512) void k_aggrD(
    const unsigned short* __restrict__ SE, const unsigned short* __restrict__ IE,
    const int* __restrict__ sidx, const int* __restrict__ iidx,
    unsigned short* __restrict__ G) {
    aggr_role<true>(SE, IE, sidx, iidx, G, blockIdx.x);
}

__global__ __launch_bounds__(512) void k_embedS(
    const unsigned short* __restrict__ X, const unsigned short* __restrict__ W2t,
    const float* __restrict__ b2, unsigned short* __restrict__ Y) {
    embed_role<128, false>(blockIdx.x, gridDim.x, NTILES, X, nullptr, W2t, b2, Y, nullptr);
}

__global__ __launch_bounds__(512) void k_update256(
    const unsigned short* __restrict__ G, const unsigned short* __restrict__ H,
    const unsigned short* __restrict__ Wut, const float* __restrict__ bu,
    float* __restrict__ Yf, unsigned short* __restrict__ Yb, int writeb) {
    update_role<256>(blockIdx.x, gridDim.x, G, nullptr, H, Wut, bu, Yf, Yb, writeb);
}

__global__ __launch_bounds__(512) void k_update384(
    const unsigned short* __restrict__ Gs, const unsigned short* __restrict__ Gi,
    const unsigned short* __restrict__ H,
    const unsigned short* __restrict__ Wut, const float* __restrict__ bu,
    float* __restrict__ Yf) {
    update_role<384>(blockIdx.x, gridDim.x, Gs, Gi, H, Wut, bu, Yf, nullptr, 0);
}

extern "C" void kernel_launch(void* const* d_in, const int* in_sizes, int n_in,
                              void* d_out, int out_size, void* d_ws, size_t ws_size,
                              hipStream_t stream) {
    const float* state    = (const float*)d_in[0];
    const float* internal = (const float*)d_in[1];
    const int*   sidx     = (const int*)d_in[2];
    const int*   iidx     = (const int*)d_in[3];
    const float* W1  = (const float*)d_in[4];
    const float* b1  = (const float*)d_in[5];
    const float* W2  = (const float*)d_in[6];
    const float* b2  = (const float*)d_in[7];
    const float* Wu1 = (const float*)d_in[8];
    const float* bu1 = (const float*)d_in[9];
    const float* Wu2 = (const float*)d_in[10];
    const float* bu2 = (const float*)d_in[11];

    float* hu1 = (float*)d_out;
    float* hu2 = hu1 + (size_t)ROWS * HID;

    unsigned short* W1t     = (unsigned short*)d_ws;       // 8192
    unsigned short* W2t     = W1t + 8192;                  // 16384
    unsigned short* Wu1t    = W2t + 16384;                 // 32768
    unsigned short* Wu2t384 = Wu1t + 32768;                // 49152
    unsigned short* Wu2t256 = Wu2t384 + 49152;             // 32768 (fallback)
    unsigned short* buf0 = Wu2t256 + 32768;                // weights 139264 total
    unsigned short* buf1 = buf0 + (size_t)ROWS * HID;      // 10.24M elems each
    unsigned short* buf2 = buf1 + (size_t)ROWS * HID;
    unsigned short* buf3 = buf2 + (size_t)ROWS * HID;
    unsigned short* buf4 = buf3 + (size_t)ROWS * HID;

    const size_t need_big = ((size_t)139264 + 5 * (size_t)ROWS * HID) * 2;
    const bool big = ws_size >= need_big;

    dim3 b256(256), b512(512);

    wconv_all<<<544, b256, 0, stream>>>(W1, W2, Wu1, Wu2,
                                        W1t, W2t, Wu1t, Wu2t384, Wu2t256);

    // K1: SE1 -> buf0, IE1 -> buf1
    k_embed1<<<1250, b512, 0, stream>>>(state, internal, W1t, b1, buf0, buf1);

    if (big) {
        // K2: [aggr1 -> buf2] || [se2 = relu(SE1@W2) -> buf3]
        k_co1<<<COGRID, b512, 0, stream>>>(buf0, buf1, sidx, iidx, buf2,
                                           W2t, b2, buf3);
        // K3: hu1 = relu([G1|IE1]@Wu1+bu1) -> d_out f32 + bf16 -> buf0 (SE1 dead)
        k_update256<<<1250, b512, 0, stream>>>(buf2, buf1, Wu1t, bu1, hu1, buf0, 1);
        // K4: [aggr2SE: gather(se2,sidx) -> buf2] || [ie2 = relu(hu1b@W2) -> buf1]
        k_co2<<<COGRID, b512, 0, stream>>>(buf3, sidx, buf2, buf0, W2t, b2, buf1);
        // K5: aggr2IE: gather(ie2, iidx) -> buf4
        k_aggrS<<<AGRID, b512, 0, stream>>>(buf1, iidx, buf4);
        // K6: hu2 = relu([Gs|Gi|ie2]@Wu2_384+bu2) -> d_out
        k_update384<<<1250, b512, 0, stream>>>(buf2, buf4, buf1, Wu2t384, bu2, hu2);
    } else {
        // 3-buffer sequential fallback; hu2 region doubles as bf16 G scratch.
        unsigned short* Ghu2 = (unsigned short*)hu2;
        k_aggrD<<<AGRID, b512, 0, stream>>>(buf0, buf1, sidx, iidx, Ghu2);
        k_update256<<<1250, b512, 0, stream>>>(Ghu2, buf1, Wu1t, bu1, hu1, buf2, 1);
        // se2: buf0 -> buf1 (IE1 dead); ie2: buf2 -> buf0 (SE1 dead)
        k_embedS<<<1250, b512, 0, stream>>>(buf0, W2t, b2, buf1);
        k_embedS<<<1250, b512, 0, stream>>>(buf2, W2t, b2, buf0);
        k_aggrD<<<AGRID, b512, 0, stream>>>(buf1, buf0, sidx, iidx, buf2);
        k_update256<<<1250, b512, 0, stream>>>(buf2, buf0, Wu2t256, bu2, hu2, nullptr, 0);
    }
}